// Round 7
// baseline (863.633 us; speedup 1.0000x reference)
//
#include <hip/hip_runtime.h>
#include <stdint.h>

// Problem dims (fixed by reference)
#define TOKENS 8192
#define DIN    4096
#define DOUT   4096

typedef short bf16x8 __attribute__((ext_vector_type(8)));  // 8 bf16 = 4 VGPRs
typedef float f32x4  __attribute__((ext_vector_type(4)));  // MFMA 16x16 accum

// ---- fp32 -> bf16 round-to-nearest-even (inputs finite) ----
__device__ __forceinline__ unsigned short f2bf(float f) {
    union { float f; unsigned int u; } v; v.f = f;
    return (unsigned short)((v.u + 0x7fffu + ((v.u >> 16) & 1u)) >> 16);
}

// ---- ternary int {-1,0,1} -> bf16 bit pattern (2 selects, no float math) ----
__device__ __forceinline__ unsigned short tern2bf(int v) {
    return v == 0 ? (unsigned short)0u
                  : (v > 0 ? (unsigned short)0x3F80u : (unsigned short)0xBF80u);
}

// ---- async global->LDS, 16B/lane; LDS dest = wave-uniform base + lane*16 ----
__device__ __forceinline__ void gload_lds16(const unsigned short* g, unsigned short* l) {
    __builtin_amdgcn_global_load_lds(
        (const __attribute__((address_space(1))) unsigned int*)g,
        (__attribute__((address_space(3))) unsigned int*)l,
        16, 0, 0);
}

// ================= fused prologue: one kernel, two jobs =================
#define WBLKS 1024
#define XBLKS 2048

__global__ __launch_bounds__(256) void fused_cvt(
    const float* __restrict__ x, const int* __restrict__ W,
    unsigned short* __restrict__ xb, unsigned short* __restrict__ Wt) {
    __shared__ unsigned short lds[64][264];   // [n_local][k_local], pitch 264
    const int t = threadIdx.x;

    if (blockIdx.x < WBLKS) {
        // ---- W transpose part: tile k0..k0+255, n0..n0+63 ----
        const int b  = blockIdx.x;
        const int k0 = (b >> 6) * 256;        // 16 k-tiles
        const int n0 = (b & 63) * 64;         // 64 n-tiles
        const int nl = 4 * (t & 15);          // n_local base this thread fills
#pragma unroll
        for (int it = 0; it < 16; ++it) {
            const int r = (t >> 4) + 16 * it; // k_local
            int4 v = *(const int4*)&W[(size_t)(k0 + r) * DOUT + n0 + nl];
            lds[nl + 0][r] = tern2bf(v.x);
            lds[nl + 1][r] = tern2bf(v.y);
            lds[nl + 2][r] = tern2bf(v.z);
            lds[nl + 3][r] = tern2bf(v.w);
        }
        __syncthreads();
        const int n = t >> 2;                 // 0..63
        const int s = t & 3;
        unsigned short* drow = Wt + (size_t)(n0 + n) * DIN + k0;
#pragma unroll
        for (int u = 0; u < 8; ++u) {
            const int k = u * 32 + s * 8;     // lanes 0-3 cover 64B contiguous
            *(uint4*)&drow[k] = *(const uint4*)&lds[n][k];
        }
    } else {
        // ---- x convert part: 8 chunks of 8 floats per thread ----
        const int b2 = blockIdx.x - WBLKS;    // 0..2047
        const int stride = XBLKS * 256;       // chunks per sweep
        int c = b2 * 256 + t;
        const float4* x4 = (const float4*)x;
        uint4* o = (uint4*)xb;                // 8 bf16 = 16B per chunk
#pragma unroll
        for (int j = 0; j < 8; ++j, c += stride) {
            float4 a = x4[2 * c];
            float4 bvec = x4[2 * c + 1];
            uint4 p;
            p.x = (unsigned)f2bf(a.x)    | ((unsigned)f2bf(a.y) << 16);
            p.y = (unsigned)f2bf(a.z)    | ((unsigned)f2bf(a.w) << 16);
            p.z = (unsigned)f2bf(bvec.x) | ((unsigned)f2bf(bvec.y) << 16);
            p.w = (unsigned)f2bf(bvec.z) | ((unsigned)f2bf(bvec.w) << 16);
            o[c] = p;
        }
    }
}

// ========== main GEMM: 256x256, BK=64, A direct-from-global, B in LDS ==========
// R7: additive-regime fix. Per-phase LDS cost was ~512 cyc (48 b128 reads +
// 16 KB staging writes) serialized with the 620-cyc MFMA window across 5 sync
// variants. A-fragments have a perfectly-coalesced GLOBAL form (lanes
// {l,l+16,l+32,l+48} cover one row's 4 k-quads = 64 B lines fully used), so:
//   - drop sA entirely; prefetch A-frags 1 phase ahead into reg ping-pong
//     (af0/af1); compiler inserts counted vmcnt before consuming MFMAs.
//   - keep B in LDS with the R4-verified 2-deep/two-ahead ledger
//     (stages at p2/p3/p6/p7; buf read at its QD0 phase only).
// LDS/phase drops to ~190 cyc (hideable); A comes from L2 (~22 TB/s chip-wide
// demand, 64% of ceiling; same-by blocks share panels within an XCD via T1).
//
// Hand waits (the only ones): VM16 at p3 and p7 pre-barrier = cross-wave
// confirmation of the B-stage issued 4 phases earlier (newest 16 outstanding =
// last 3 phases' issues: p3: {p1A:4,p2A+B:6,p3A+B:6}; draining to 16 forces the
// 2-iter-old B gloads complete in EVERY wave before the barrier that precedes
// the ds_read of that buffer). One group of safety margin vs issue reorder.
// Compiler-only fences (""::"memory") pin loads into their phase (R3 failure
// mode: sunk reads). B reads at QD0 use compiler-counted lgkm.
#define BM 256
#define BN 256
#define BK 64

#define STG_B(bufi, h, kt)                                                  \
    do {                                                                    \
        gload_lds16(gB + (size_t)((h) * 128) * DIN + (kt),                  \
                    &sB[bufi][(h) * 8192 + wave * 1024]);                   \
        gload_lds16(gB + (size_t)((h) * 128 + 8) * DIN + (kt),              \
                    &sB[bufi][(h) * 8192 + wave * 1024 + 512]);             \
    } while (0)

#define FEN  asm volatile("" ::: "memory")
#define BARF do { FEN; __builtin_amdgcn_s_barrier(); FEN; } while (0)
#define VM16 asm volatile("s_waitcnt vmcnt(16)" ::: "memory")
#define VM12 asm volatile("s_waitcnt vmcnt(12)" ::: "memory")
#define VM4  asm volatile("s_waitcnt vmcnt(4)" ::: "memory")

// Prefetch A-frags for quadrant QD of the K-tile at TILEKT into set NX.
// Lane layout: row = mrow (16 rows), col quad = kgrp -> 64B-coalesced lines.
#define PREF_A(NX, TILEKT, QD)                                              \
    do {                                                                    \
        _Pragma("unroll") for (int m2 = 0; m2 < 2; ++m2) {                  \
            NX[m2][0] = *(const bf16x8*)&gAf[(size_t)(((QD) * 2 + m2) * 16) \
                                             * DIN + (TILEKT)];             \
            NX[m2][1] = *(const bf16x8*)&gAf[(size_t)(((QD) * 2 + m2) * 16) \
                                             * DIN + (TILEKT) + 32];        \
        }                                                                   \
    } while (0)

// 8 ds_read_b128: all B-frags of LDS buffer BUF (resident across 4 phases)
#define RD_B(BUF)                                                           \
    do {                                                                    \
        _Pragma("unroll") for (int ni = 0; ni < 4; ++ni) {                  \
            bfr[ni][0] = *(const bf16x8*)&sB[BUF][rowB + ni * 1024 + q80];  \
            bfr[ni][1] = *(const bf16x8*)&sB[BUF][rowB + ni * 1024 + q81];  \
        }                                                                   \
    } while (0)

// 16 MFMA: quadrant QD from A-set AF + resident bfr
#define MFMA_Q(AF, QD)                                                      \
    do {                                                                    \
        __builtin_amdgcn_s_setprio(1);                                      \
        _Pragma("unroll") for (int ks = 0; ks < 2; ++ks)                    \
            _Pragma("unroll") for (int m2 = 0; m2 < 2; ++m2)                \
                _Pragma("unroll") for (int ni = 0; ni < 4; ++ni)            \
                    acc[(QD) * 2 + m2][ni] =                                \
                        __builtin_amdgcn_mfma_f32_16x16x32_bf16(            \
                            AF[m2][ks], bfr[ni][ks],                        \
                            acc[(QD) * 2 + m2][ni], 0, 0, 0);               \
        __builtin_amdgcn_s_setprio(0);                                      \
    } while (0)

__global__ __launch_bounds__(512, 2) void gemm_bt(
    const unsigned short* __restrict__ A,   // [M][K] bf16
    const unsigned short* __restrict__ B,   // [N][K] bf16 (W transposed)
    float* __restrict__ C) {                // [M][N] fp32
    const int K = DIN, N = DOUT;

    __shared__ __align__(16) unsigned short sB[2][BN * BK];  // 2 x 32 KB (B only)

    const int tid  = threadIdx.x;
    const int wave = tid >> 6;
    const int lane = tid & 63;
    const int wm = wave >> 2;               // 0..1  (M)
    const int wn = wave & 3;                // 0..3  (N)

    // ---- T1: XCD-aware bijective block swizzle (512 wgs, 8 XCDs, 64/XCD) ----
    const int wg  = blockIdx.x + gridDim.x * blockIdx.y;   // hardware linear id
    const int xcd = wg & 7;
    const int idx = wg >> 3;                               // 0..63 within XCD
    const int bx  = (xcd & 1) * 8 + (idx & 7);             // 0..15  (N tiles)
    const int by  = (xcd >> 1) * 8 + (idx >> 3);           // 0..31  (M tiles)

    // ---- B staging addressing: wave w stages rows 16w..16w+15 of each half ----
    const int lrow = lane >> 3;             // 0..7 row within 8-row chunk
    const int qsrc = (lane & 7) ^ lrow;     // pre-swizzled global k-quad
    const unsigned short* gB =
        B + (size_t)(bx * BN + wave * 16 + lrow) * K + qsrc * 8;

    // ---- fragment addressing ----
    const int mrow = lane & 15;
    const int kgrp = lane >> 4;             // 0..3
    const int xr   = lane & 7;              // = row&7 of the frag row
    const int q80  = ((kgrp ^ xr) << 3);        // ks=0 swizzled quad * 8
    const int q81  = (((4 | kgrp) ^ xr) << 3);  // ks=1
    const int rowB = (wn * 64 + mrow) << 6;     // *64 elems/row

    // A direct-global per-lane base: row = block M-base + wave-M half + mrow
    const unsigned short* gAf =
        A + (size_t)(by * BM + wm * 128 + mrow) * K + kgrp * 8;

    f32x4 acc[8][4];
#pragma unroll
    for (int i = 0; i < 8; ++i)
#pragma unroll
        for (int j = 0; j < 4; ++j) {
            f32x4 z = {0.f, 0.f, 0.f, 0.f};
            acc[i][j] = z;
        }
    bf16x8 bfr[4][2];     // B-frags: resident across a K-tile's 4 phases
    bf16x8 af0[2][2];     // A-frag ping (even phases' MFMA)
    bf16x8 af1[2][2];     // A-frag pong (odd phases' MFMA)

    // ---- prologue: stage B0, B1 (8 gloads); confirm B0, leave B1 flying ----
    STG_B(0, 0, 0);
    STG_B(0, 1, 0);
    STG_B(1, 0, 64);
    STG_B(1, 1, 64);
    VM4;                  // B0 (oldest 4) confirmed; B1 (4) in flight
    BARF;
    PREF_A(af0, 0, 0);    // tile0 QD0 -> af0 (consumed at first p0)

    // ---- main loop: 31 iters (tiles 0..61) ----
    for (int kt = 0; kt + 256 <= K; kt += 128) {
        // p0
        PREF_A(af1, kt, 1);
        RD_B(0);
        BARF; MFMA_Q(af0, 0); BARF;
        // p1
        PREF_A(af0, kt, 2);
        BARF; MFMA_Q(af1, 1); BARF;
        // p2
        PREF_A(af1, kt, 3);
        STG_B(0, 0, kt + 128);
        BARF; MFMA_Q(af0, 2); BARF;
        // p3: VM16 confirms B1 (staged prev p6/p7) in all waves before p4's read
        PREF_A(af0, kt + 64, 0);
        STG_B(0, 1, kt + 128);
        VM16;
        BARF; MFMA_Q(af1, 3); BARF;
        // p4
        PREF_A(af1, kt + 64, 1);
        RD_B(1);
        BARF; MFMA_Q(af0, 0); BARF;
        // p5
        PREF_A(af0, kt + 64, 2);
        BARF; MFMA_Q(af1, 1); BARF;
        // p6
        PREF_A(af1, kt + 64, 3);
        STG_B(1, 0, kt + 192);
        BARF; MFMA_Q(af0, 2); BARF;
        // p7: VM16 confirms B0 (staged this p2/p3) before next p0's read
        PREF_A(af0, kt + 128, 0);
        STG_B(1, 1, kt + 192);
        VM16;
        BARF; MFMA_Q(af1, 3); BARF;
    }

    // ---- peeled tail: tiles 62 (buf0) and 63 (buf1); no more staging ----
    {
        const int kt = K - 128;
        PREF_A(af1, kt, 1);
        RD_B(0);
        BARF; MFMA_Q(af0, 0); BARF;

        PREF_A(af0, kt, 2);
        BARF; MFMA_Q(af1, 1); BARF;

        PREF_A(af1, kt, 3);
        BARF; MFMA_Q(af0, 2); BARF;

        PREF_A(af0, kt + 64, 0);
        VM12;             // confirm B1 (staged prev p6/p7): newer = 16 A-loads
        BARF; MFMA_Q(af1, 3); BARF;

        PREF_A(af1, kt + 64, 1);
        RD_B(1);
        BARF; MFMA_Q(af0, 0); BARF;

        PREF_A(af0, kt + 64, 2);
        BARF; MFMA_Q(af1, 1); BARF;

        PREF_A(af1, kt + 64, 3);
        BARF; MFMA_Q(af0, 2); BARF;

        BARF; MFMA_Q(af1, 3);
    }

    // ---- epilogue: C/D layout col=lane&15, row=(lane>>4)*4+reg; NT stores ----
    float* Cw = C + (size_t)(by * BM + wm * 128 + kgrp * 4) * N
                + (size_t)(bx * BN + wn * 64 + mrow);
#pragma unroll
    for (int mi = 0; mi < 8; ++mi)
#pragma unroll
        for (int ni = 0; ni < 4; ++ni)
#pragma unroll
            for (int r = 0; r < 4; ++r)
                __builtin_nontemporal_store(acc[mi][ni][r],
                                            &Cw[(size_t)(mi * 16 + r) * N + ni * 16]);
}

// ============ safety-net fallback if ws is too small (slow but correct) ============
__global__ void gemm_naive(const float* __restrict__ x, const int* __restrict__ W,
                           float* __restrict__ out) {
    int n = blockIdx.x * blockDim.x + threadIdx.x;
    int t = blockIdx.y;
    const float* xr = x + (size_t)t * DIN;
    float acc = 0.f;
    for (int k = 0; k < DIN; ++k)
        acc += xr[k] * (float)W[(size_t)k * DOUT + n];
    out[(size_t)t * DOUT + n] = acc;
}

extern "C" void kernel_launch(void* const* d_in, const int* in_sizes, int n_in,
                              void* d_out, int out_size, void* d_ws, size_t ws_size,
                              hipStream_t stream) {
    const float* x = (const float*)d_in[0];
    const int*   W = (const int*)d_in[1];
    float* out = (float*)d_out;

    const size_t xb_elems = (size_t)TOKENS * DIN;           // 64 MB bf16
    const size_t wt_elems = (size_t)DIN * DOUT;             // 32 MB bf16
    const size_t need = (xb_elems + wt_elems) * sizeof(unsigned short);

    if (ws_size < need) {   // should not happen; correctness safety net
        dim3 g(DOUT / 256, TOKENS);
        gemm_naive<<<g, 256, 0, stream>>>(x, W, out);
        return;
    }

    unsigned short* xb = (unsigned short*)d_ws;
    unsigned short* Wt = xb + xb_elems;

    fused_cvt<<<WBLKS + XBLKS, 256, 0, stream>>>(x, W, xb, Wt);

    dim3 grid(DOUT / BN, TOKENS / BM);   // (16, 32)
    gemm_bt<<<grid, 512, 0, stream>>>(xb, Wt, out);
}

// Round 9
// 476.540 us; speedup vs baseline: 1.8123x; 1.8123x over previous
//
#include <hip/hip_runtime.h>
#include <stdint.h>

// Problem dims (fixed by reference)
#define TOKENS 8192
#define DIN    4096
#define DOUT   4096

typedef short bf16x8 __attribute__((ext_vector_type(8)));  // 8 bf16 = 4 VGPRs
typedef float f32x4  __attribute__((ext_vector_type(4)));  // MFMA 16x16 accum
typedef int   i32x4  __attribute__((ext_vector_type(4)));  // NT-loadable int4
typedef float f32x4v __attribute__((ext_vector_type(4)));  // NT-loadable float4

// ---- fp32 -> bf16 round-to-nearest-even (inputs finite) ----
__device__ __forceinline__ unsigned short f2bf(float f) {
    union { float f; unsigned int u; } v; v.f = f;
    return (unsigned short)((v.u + 0x7fffu + ((v.u >> 16) & 1u)) >> 16);
}

// ---- ternary int {-1,0,1} -> bf16 bit pattern (2 selects, no float math) ----
__device__ __forceinline__ unsigned short tern2bf(int v) {
    return v == 0 ? (unsigned short)0u
                  : (v > 0 ? (unsigned short)0x3F80u : (unsigned short)0xBF80u);
}

// ---- async global->LDS, 16B/lane; LDS dest = wave-uniform base + lane*16 ----
__device__ __forceinline__ void gload_lds16(const unsigned short* g, unsigned short* l) {
    __builtin_amdgcn_global_load_lds(
        (const __attribute__((address_space(1))) unsigned int*)g,
        (__attribute__((address_space(3))) unsigned int*)l,
        16, 0, 0);
}

// ================= fused prologue: one kernel, two jobs =================
// R9 (= R8 with compile fix): W-part uses 4-row register micro-transpose +
// uint2 LDS writes (16 writes/thread instead of 64 conflicted b16s); x and W
// are NONTEMPORAL loads (read-once; preserves L3 for xb+Wt -> gemm starts warm).
#define WBLKS 1024
#define XBLKS 2048

__global__ __launch_bounds__(256) void fused_cvt(
    const float* __restrict__ x, const int* __restrict__ W,
    unsigned short* __restrict__ xb, unsigned short* __restrict__ Wt) {
    __shared__ unsigned short lds[64][264];   // [n_local][k_local], pitch 264
    const int t = threadIdx.x;

    if (blockIdx.x < WBLKS) {
        // ---- W transpose: tile k0..k0+255 x n0..n0+63 ----
        const int b  = blockIdx.x;
        const int k0 = (b >> 6) * 256;        // 16 k-tiles
        const int n0 = (b & 63) * 64;         // 64 n-tiles
        const int kq = t >> 4;                // 0..15 (k quad group)
        const int nq = t & 15;                // 0..15 (n quad group)
#pragma unroll
        for (int it = 0; it < 4; ++it) {
            const int kb = it * 64 + kq * 4;  // k_local base (4 rows)
            const int* wp = &W[(size_t)(k0 + kb) * DOUT + n0 + nq * 4];
            i32x4 v0 = __builtin_nontemporal_load((const i32x4*)(wp));
            i32x4 v1 = __builtin_nontemporal_load((const i32x4*)(wp + DOUT));
            i32x4 v2 = __builtin_nontemporal_load((const i32x4*)(wp + 2 * DOUT));
            i32x4 v3 = __builtin_nontemporal_load((const i32x4*)(wp + 3 * DOUT));
            uint2 p;
            // n-col 0: rows kb..kb+3 packed along k
            p.x = (unsigned)tern2bf(v0.x) | ((unsigned)tern2bf(v1.x) << 16);
            p.y = (unsigned)tern2bf(v2.x) | ((unsigned)tern2bf(v3.x) << 16);
            *(uint2*)&lds[nq * 4 + 0][kb] = p;
            p.x = (unsigned)tern2bf(v0.y) | ((unsigned)tern2bf(v1.y) << 16);
            p.y = (unsigned)tern2bf(v2.y) | ((unsigned)tern2bf(v3.y) << 16);
            *(uint2*)&lds[nq * 4 + 1][kb] = p;
            p.x = (unsigned)tern2bf(v0.z) | ((unsigned)tern2bf(v1.z) << 16);
            p.y = (unsigned)tern2bf(v2.z) | ((unsigned)tern2bf(v3.z) << 16);
            *(uint2*)&lds[nq * 4 + 2][kb] = p;
            p.x = (unsigned)tern2bf(v0.w) | ((unsigned)tern2bf(v1.w) << 16);
            p.y = (unsigned)tern2bf(v2.w) | ((unsigned)tern2bf(v3.w) << 16);
            *(uint2*)&lds[nq * 4 + 3][kb] = p;
        }
        __syncthreads();
        const int n = t >> 2;                 // 0..63
        const int s = t & 3;
        unsigned short* drow = Wt + (size_t)(n0 + n) * DIN + k0;
#pragma unroll
        for (int u = 0; u < 8; ++u) {
            const int k = u * 32 + s * 8;     // lanes 0-3 cover 64B contiguous
            *(uint4*)&drow[k] = *(const uint4*)&lds[n][k];
        }
    } else {
        // ---- x convert part: 8 chunks of 8 floats per thread ----
        const int b2 = blockIdx.x - WBLKS;    // 0..2047
        const int stride = XBLKS * 256;       // chunks per sweep
        int c = b2 * 256 + t;
        const f32x4v* x4 = (const f32x4v*)x;
        uint4* o = (uint4*)xb;                // 8 bf16 = 16B per chunk
#pragma unroll
        for (int j = 0; j < 8; ++j, c += stride) {
            f32x4v a = __builtin_nontemporal_load(&x4[2 * c]);
            f32x4v bvec = __builtin_nontemporal_load(&x4[2 * c + 1]);
            uint4 p;
            p.x = (unsigned)f2bf(a.x)    | ((unsigned)f2bf(a.y) << 16);
            p.y = (unsigned)f2bf(a.z)    | ((unsigned)f2bf(a.w) << 16);
            p.z = (unsigned)f2bf(bvec.x) | ((unsigned)f2bf(bvec.y) << 16);
            p.w = (unsigned)f2bf(bvec.z) | ((unsigned)f2bf(bvec.w) << 16);
            o[c] = p;
        }
    }
}

// ================= main GEMM: 256x256, BK=64, faithful m201 8-phase =================
// (R4-verified, race-free, 264 us. Held constant to isolate the fused_cvt
// experiment.) Phase = [reads][stage][vmcnt@group-end][lgkm8 on 12-read phases]
// BAR lgkm0 setprio(1) 16xMFMA setprio(0) BAR.
// Ledger: p0:A+1h0 p1:A+1h1 p2:B+2h0 p3:B+2h1+VM4 p4:A+2h0 p5:A+2h1 p6:B+3h0
// p7:B+3h1+VM4. Never drains vmcnt to 0 in the loop.
#define BM 256
#define BN 256
#define BK 64

#define STAGE_A(bufi, h, kt)                                                        \
    do {                                                                            \
        gload_lds16(gA + (size_t)((h) * 128) * DIN + (kt),                          \
                    &sA[bufi][(h) * 8192 + wave * 1024]);                           \
        gload_lds16(gA + (size_t)((h) * 128 + 8) * DIN + (kt),                      \
                    &sA[bufi][(h) * 8192 + wave * 1024 + 512]);                     \
    } while (0)

#define STAGE_B(bufi, h, kt)                                                        \
    do {                                                                            \
        gload_lds16(gB + (size_t)((h) * 128) * DIN + (kt),                          \
                    &sB[bufi][(h) * 8192 + wave * 1024]);                           \
        gload_lds16(gB + (size_t)((h) * 128 + 8) * DIN + (kt),                      \
                    &sB[bufi][(h) * 8192 + wave * 1024 + 512]);                     \
    } while (0)

#define BAR __builtin_amdgcn_s_barrier()
#define VM4 asm volatile("s_waitcnt vmcnt(4)" ::: "memory")
#define VM0 asm volatile("s_waitcnt vmcnt(0)" ::: "memory")
#define LG8 asm volatile("s_waitcnt lgkmcnt(8)" ::: "memory")

// One phase: same-phase fragment consumption (m201-faithful).
#define PH(BUF, QD, STG, TAIL)                                                      \
    {                                                                               \
        if ((QD) == 0) {                                                            \
            _Pragma("unroll") for (int ni = 0; ni < 4; ++ni) {                      \
                bfr[ni][0] = *(const bf16x8*)&sB[BUF][rowB + ni * 1024 + q80];      \
                bfr[ni][1] = *(const bf16x8*)&sB[BUF][rowB + ni * 1024 + q81];      \
            }                                                                       \
        }                                                                           \
        bf16x8 af[2][2];                                                            \
        _Pragma("unroll") for (int m2 = 0; m2 < 2; ++m2) {                          \
            af[m2][0] = *(const bf16x8*)&sA[BUF][rowA + ((QD)*2 + m2) * 1024 + q80];\
            af[m2][1] = *(const bf16x8*)&sA[BUF][rowA + ((QD)*2 + m2) * 1024 + q81];\
        }                                                                           \
        STG;                                                                        \
        TAIL;                                                                       \
        if ((QD) == 0) LG8;                                                         \
        BAR;                                                                        \
        asm volatile("s_waitcnt lgkmcnt(0)" ::: "memory");                          \
        __builtin_amdgcn_s_setprio(1);                                              \
        _Pragma("unroll") for (int ks = 0; ks < 2; ++ks)                            \
            _Pragma("unroll") for (int m2 = 0; m2 < 2; ++m2)                        \
                _Pragma("unroll") for (int ni = 0; ni < 4; ++ni)                    \
                    acc[(QD)*2 + m2][ni] = __builtin_amdgcn_mfma_f32_16x16x32_bf16( \
                        af[m2][ks], bfr[ni][ks], acc[(QD)*2 + m2][ni], 0, 0, 0);    \
        __builtin_amdgcn_s_setprio(0);                                              \
        BAR;                                                                        \
    }

__global__ __launch_bounds__(512, 2) void gemm_bt(
    const unsigned short* __restrict__ A,   // [M][K] bf16
    const unsigned short* __restrict__ B,   // [N][K] bf16 (W transposed)
    float* __restrict__ C) {                // [M][N] fp32
    const int K = DIN, N = DOUT;

    __shared__ __align__(16) unsigned short sA[2][BM * BK];  // 2 x 32 KB
    __shared__ __align__(16) unsigned short sB[2][BN * BK];  // 2 x 32 KB

    const int tid  = threadIdx.x;
    const int wave = tid >> 6;
    const int lane = tid & 63;
    const int wm = wave >> 2;               // 0..1  (M)
    const int wn = wave & 3;                // 0..3  (N)

    // ---- T1: XCD-aware bijective block swizzle (512 wgs, 8 XCDs, 64/XCD) ----
    const int wg  = blockIdx.x + gridDim.x * blockIdx.y;   // hardware linear id
    const int xcd = wg & 7;
    const int idx = wg >> 3;                               // 0..63 within XCD
    const int bx  = (xcd & 1) * 8 + (idx & 7);             // 0..15  (N tiles)
    const int by  = (xcd >> 1) * 8 + (idx >> 3);           // 0..31  (M tiles)

    // ---- staging addressing: wave w stages rows 16w..16w+15 of each half ----
    const int lrow = lane >> 3;             // 0..7 row within 8-row chunk
    const int qsrc = (lane & 7) ^ lrow;     // pre-swizzled global k-quad
    const unsigned short* gA =
        A + (size_t)(by * BM + wave * 16 + lrow) * K + qsrc * 8;
    const unsigned short* gB =
        B + (size_t)(bx * BN + wave * 16 + lrow) * K + qsrc * 8;

    // ---- fragment read addressing (swizzled ds_read) ----
    const int mrow = lane & 15;
    const int kgrp = lane >> 4;             // 0..3
    const int xr   = lane & 7;              // = row&7 of the frag row
    const int q80  = ((kgrp ^ xr) << 3);        // ks=0 swizzled quad * 8
    const int q81  = (((4 | kgrp) ^ xr) << 3);  // ks=1
    const int rowA = (wm * 128 + mrow) << 6;    // *64 elems/row
    const int rowB = (wn * 64 + mrow) << 6;

    f32x4 acc[8][4];
#pragma unroll
    for (int i = 0; i < 8; ++i)
#pragma unroll
        for (int j = 0; j < 4; ++j) {
            f32x4 z = {0.f, 0.f, 0.f, 0.f};
            acc[i][j] = z;
        }
    bf16x8 bfr[4][2];     // B-frags: resident across a K-tile's 4 phases

    // ---- prologue: A0, B0 (tile0) + B1 (tile1 B, two-ahead pattern) ----
    STAGE_A(0, 0, 0);
    STAGE_A(0, 1, 0);
    STAGE_B(0, 0, 0);
    STAGE_B(0, 1, 0);
    STAGE_B(1, 0, 64);
    STAGE_B(1, 1, 64);
    VM4;                  // confirm A0,B0; B1 (4 loads) stays in flight
    BAR;

    // ---- main loop: g = 0..30 (tiles 0..61), branch-free ----
    for (int kt = 0; kt + 256 <= K; kt += 128) {
        PH(0, 0, STAGE_A(1, 0, kt + 64), )       // p0
        PH(0, 1, STAGE_A(1, 1, kt + 64), )       // p1
        PH(0, 2, STAGE_B(0, 0, kt + 128), )      // p2
        PH(0, 3, STAGE_B(0, 1, kt + 128), VM4)   // p3
        PH(1, 0, STAGE_A(0, 0, kt + 128), )      // p4
        PH(1, 1, STAGE_A(0, 1, kt + 128), )      // p5
        PH(1, 2, STAGE_B(1, 0, kt + 192), )      // p6
        PH(1, 3, STAGE_B(1, 1, kt + 192), VM4)   // p7
    }

    // ---- peeled tail: tiles 62 (buf0) and 63 (buf1) ----
    PH(0, 0, STAGE_A(1, 0, K - 64), )
    PH(0, 1, STAGE_A(1, 1, K - 64), )
    PH(0, 2, , )
    PH(0, 3, , VM0)       // drain: A63 (+ already-confirmed B63) complete
    PH(1, 0, , )
    PH(1, 1, , )
    PH(1, 2, , )
    PH(1, 3, , )

    // ---- epilogue: C/D layout col=lane&15, row=(lane>>4)*4+reg; NT stores ----
    float* Cw = C + (size_t)(by * BM + wm * 128 + kgrp * 4) * N
                + (size_t)(bx * BN + wn * 64 + mrow);
#pragma unroll
    for (int mi = 0; mi < 8; ++mi)
#pragma unroll
        for (int ni = 0; ni < 4; ++ni)
#pragma unroll
            for (int r = 0; r < 4; ++r)
                __builtin_nontemporal_store(acc[mi][ni][r],
                                            &Cw[(size_t)(mi * 16 + r) * N + ni * 16]);
}

// ============ safety-net fallback if ws is too small (slow but correct) ============
__global__ void gemm_naive(const float* __restrict__ x, const int* __restrict__ W,
                           float* __restrict__ out) {
    int n = blockIdx.x * blockDim.x + threadIdx.x;
    int t = blockIdx.y;
    const float* xr = x + (size_t)t * DIN;
    float acc = 0.f;
    for (int k = 0; k < DIN; ++k)
        acc += xr[k] * (float)W[(size_t)k * DOUT + n];
    out[(size_t)t * DOUT + n] = acc;
}

extern "C" void kernel_launch(void* const* d_in, const int* in_sizes, int n_in,
                              void* d_out, int out_size, void* d_ws, size_t ws_size,
                              hipStream_t stream) {
    const float* x = (const float*)d_in[0];
    const int*   W = (const int*)d_in[1];
    float* out = (float*)d_out;

    const size_t xb_elems = (size_t)TOKENS * DIN;           // 64 MB bf16
    const size_t wt_elems = (size_t)DIN * DOUT;             // 32 MB bf16
    const size_t need = (xb_elems + wt_elems) * sizeof(unsigned short);

    if (ws_size < need) {   // should not happen; correctness safety net
        dim3 g(DOUT / 256, TOKENS);
        gemm_naive<<<g, 256, 0, stream>>>(x, W, out);
        return;
    }

    unsigned short* xb = (unsigned short*)d_ws;
    unsigned short* Wt = xb + xb_elems;

    fused_cvt<<<WBLKS + XBLKS, 256, 0, stream>>>(x, W, xb, Wt);

    dim3 grid(DOUT / BN, TOKENS / BM);   // (16, 32)
    gemm_bt<<<grid, 512, 0, stream>>>(xb, Wt, out);
}

// Round 10
// 476.241 us; speedup vs baseline: 1.8134x; 1.0006x over previous
//
#include <hip/hip_runtime.h>
#include <stdint.h>

// Problem dims (fixed by reference)
#define TOKENS 8192
#define DIN    4096
#define DOUT   4096

typedef short bf16x8 __attribute__((ext_vector_type(8)));  // 8 bf16 = 4 VGPRs
typedef float f32x4  __attribute__((ext_vector_type(4)));  // MFMA 16x16 accum
typedef int   i32x4  __attribute__((ext_vector_type(4)));  // NT-loadable int4
typedef float f32x4v __attribute__((ext_vector_type(4)));  // NT-loadable float4

// ---- fp32 -> bf16 round-to-nearest-even (inputs finite) ----
__device__ __forceinline__ unsigned short f2bf(float f) {
    union { float f; unsigned int u; } v; v.f = f;
    return (unsigned short)((v.u + 0x7fffu + ((v.u >> 16) & 1u)) >> 16);
}

// ---- ternary int {-1,0,1} -> bf16 bit pattern (2 selects, no float math) ----
__device__ __forceinline__ unsigned short tern2bf(int v) {
    return v == 0 ? (unsigned short)0u
                  : (v > 0 ? (unsigned short)0x3F80u : (unsigned short)0xBF80u);
}

// ---- async global->LDS, 16B/lane; LDS dest = wave-uniform base + lane*16 ----
__device__ __forceinline__ void gload_lds16(const unsigned short* g, unsigned short* l) {
    __builtin_amdgcn_global_load_lds(
        (const __attribute__((address_space(1))) unsigned int*)g,
        (__attribute__((address_space(3))) unsigned int*)l,
        16, 0, 0);
}

// ================= fused prologue (R9-verified): one kernel, two jobs =================
#define WBLKS 1024
#define XBLKS 2048

__global__ __launch_bounds__(256) void fused_cvt(
    const float* __restrict__ x, const int* __restrict__ W,
    unsigned short* __restrict__ xb, unsigned short* __restrict__ Wt) {
    __shared__ unsigned short lds[64][264];   // [n_local][k_local], pitch 264
    const int t = threadIdx.x;

    if (blockIdx.x < WBLKS) {
        // ---- W transpose: tile k0..k0+255 x n0..n0+63 ----
        const int b  = blockIdx.x;
        const int k0 = (b >> 6) * 256;        // 16 k-tiles
        const int n0 = (b & 63) * 64;         // 64 n-tiles
        const int kq = t >> 4;                // 0..15 (k quad group)
        const int nq = t & 15;                // 0..15 (n quad group)
#pragma unroll
        for (int it = 0; it < 4; ++it) {
            const int kb = it * 64 + kq * 4;  // k_local base (4 rows)
            const int* wp = &W[(size_t)(k0 + kb) * DOUT + n0 + nq * 4];
            i32x4 v0 = __builtin_nontemporal_load((const i32x4*)(wp));
            i32x4 v1 = __builtin_nontemporal_load((const i32x4*)(wp + DOUT));
            i32x4 v2 = __builtin_nontemporal_load((const i32x4*)(wp + 2 * DOUT));
            i32x4 v3 = __builtin_nontemporal_load((const i32x4*)(wp + 3 * DOUT));
            uint2 p;
            p.x = (unsigned)tern2bf(v0.x) | ((unsigned)tern2bf(v1.x) << 16);
            p.y = (unsigned)tern2bf(v2.x) | ((unsigned)tern2bf(v3.x) << 16);
            *(uint2*)&lds[nq * 4 + 0][kb] = p;
            p.x = (unsigned)tern2bf(v0.y) | ((unsigned)tern2bf(v1.y) << 16);
            p.y = (unsigned)tern2bf(v2.y) | ((unsigned)tern2bf(v3.y) << 16);
            *(uint2*)&lds[nq * 4 + 1][kb] = p;
            p.x = (unsigned)tern2bf(v0.z) | ((unsigned)tern2bf(v1.z) << 16);
            p.y = (unsigned)tern2bf(v2.z) | ((unsigned)tern2bf(v3.z) << 16);
            *(uint2*)&lds[nq * 4 + 2][kb] = p;
            p.x = (unsigned)tern2bf(v0.w) | ((unsigned)tern2bf(v1.w) << 16);
            p.y = (unsigned)tern2bf(v2.w) | ((unsigned)tern2bf(v3.w) << 16);
            *(uint2*)&lds[nq * 4 + 3][kb] = p;
        }
        __syncthreads();
        const int n = t >> 2;                 // 0..63
        const int s = t & 3;
        unsigned short* drow = Wt + (size_t)(n0 + n) * DIN + k0;
#pragma unroll
        for (int u = 0; u < 8; ++u) {
            const int k = u * 32 + s * 8;     // lanes 0-3 cover 64B contiguous
            *(uint4*)&drow[k] = *(const uint4*)&lds[n][k];
        }
    } else {
        // ---- x convert part: 8 chunks of 8 floats per thread ----
        const int b2 = blockIdx.x - WBLKS;    // 0..2047
        const int stride = XBLKS * 256;       // chunks per sweep
        int c = b2 * 256 + t;
        const f32x4v* x4 = (const f32x4v*)x;
        uint4* o = (uint4*)xb;                // 8 bf16 = 16B per chunk
#pragma unroll
        for (int j = 0; j < 8; ++j, c += stride) {
            f32x4v a = __builtin_nontemporal_load(&x4[2 * c]);
            f32x4v bvec = __builtin_nontemporal_load(&x4[2 * c + 1]);
            uint4 p;
            p.x = (unsigned)f2bf(a.x)    | ((unsigned)f2bf(a.y) << 16);
            p.y = (unsigned)f2bf(a.z)    | ((unsigned)f2bf(a.w) << 16);
            p.z = (unsigned)f2bf(bvec.x) | ((unsigned)f2bf(bvec.y) << 16);
            p.w = (unsigned)f2bf(bvec.z) | ((unsigned)f2bf(bvec.w) << 16);
            o[c] = p;
        }
    }
}

// ========= main GEMM: 256x256, BK=64, 1-barrier/phase race-free pipeline =========
// R10: R3's structure (best measured: 8 barriers/iter, ~112 cyc/barrier saved vs
// R4's 16) made FORMALLY race-free, + counted LGK4 with SB0 pinning.
// Phase: [reads (next-phase A-quad; +B-burst at p0/p4)] [stage half-tile]
//        [VM2 at p2/p6] BAR LGK4 SB0 setprio(1) 16xMFMA setprio(0)
//
// Stage ledger per iter (tiles t0=buf0@kt, t1=buf1@kt+64):
//   p0/p1: A@kt+64 -> sA[1]     p2/p3: B@kt+128 -> sB[0]
//   p4/p5: A@kt+128 -> sA[0]    p6/p7: B@kt+192 -> sB[1]
// VM2@p2 (outstanding 10 -> 2): confirms leftover B(cur buf1, 4) + A@kt+64 (4);
//   leaves B@kt+128 h0. BAR@p2 precedes p3's sA[1] read => race-free.
// VM2@p6 (10 -> 2): confirms B@kt+128 + A@kt+128; leaves B@kt+192 h0. BAR@p6
//   precedes p7's sA[0] read and next-p0's sB[0] read => race-free.
// WAR: every buffer's last read phase r has its reads drained by LGK4@r+1,
//   which precedes BAR@r+1, which precedes the overwriting stage issue@r+2+.
// LGK4 correctness: DS ops complete in order; each phase issues exactly 4 A-reads
//   last (B-burst pinned BEFORE them by SB0 at p0/p4), so "allow 4 newest" ==
//   "everything needed by this phase's MFMA is done".
// Never drains vmcnt to 0 in the main loop. Tail: VM0 at p2 (A@K-64 h1 must be
//   confirmed; no further stages).
#define BM 256
#define BN 256
#define BK 64

#define STAGE_A(bufi, h, kt)                                                \
    do {                                                                    \
        gload_lds16(gA + (size_t)((h) * 128) * DIN + (kt),                  \
                    &sA[bufi][(h) * 8192 + wave * 1024]);                   \
        gload_lds16(gA + (size_t)((h) * 128 + 8) * DIN + (kt),              \
                    &sA[bufi][(h) * 8192 + wave * 1024 + 512]);             \
    } while (0)

#define STAGE_B(bufi, h, kt)                                                \
    do {                                                                    \
        gload_lds16(gB + (size_t)((h) * 128) * DIN + (kt),                  \
                    &sB[bufi][(h) * 8192 + wave * 1024]);                   \
        gload_lds16(gB + (size_t)((h) * 128 + 8) * DIN + (kt),              \
                    &sB[bufi][(h) * 8192 + wave * 1024 + 512]);             \
    } while (0)

#define BAR  __builtin_amdgcn_s_barrier()
#define SB0  __builtin_amdgcn_sched_barrier(0)
#define VM4  asm volatile("s_waitcnt vmcnt(4)" ::: "memory")
#define VM2  asm volatile("s_waitcnt vmcnt(2)" ::: "memory")
#define VM0  asm volatile("s_waitcnt vmcnt(0)" ::: "memory")
#define LGK4 asm volatile("s_waitcnt lgkmcnt(4)" ::: "memory")
#define LGK0 asm volatile("s_waitcnt lgkmcnt(0)" ::: "memory")

// 8 ds_read_b128: all B-frags of LDS buffer BUF (resident across 4 phases)
#define RD_B(BUF)                                                           \
    do {                                                                    \
        _Pragma("unroll") for (int ni = 0; ni < 4; ++ni) {                  \
            bfr[ni][0] = *(const bf16x8*)&sB[BUF][rowB + ni * 1024 + q80];  \
            bfr[ni][1] = *(const bf16x8*)&sB[BUF][rowB + ni * 1024 + q81];  \
        }                                                                   \
    } while (0)

// 4 ds_read_b128: A-frags, quadrant QD of buffer BUF -> register set AF
#define RD_A(AF, BUF, QD)                                                   \
    do {                                                                    \
        _Pragma("unroll") for (int m2 = 0; m2 < 2; ++m2) {                  \
            AF[m2][0] =                                                     \
                *(const bf16x8*)&sA[BUF][rowA + ((QD)*2 + m2) * 1024 + q80];\
            AF[m2][1] =                                                     \
                *(const bf16x8*)&sA[BUF][rowA + ((QD)*2 + m2) * 1024 + q81];\
        }                                                                   \
    } while (0)

// 16 MFMA: quadrant QD from A-set AF + resident bfr
#define MM(AF, QD)                                                          \
    do {                                                                    \
        __builtin_amdgcn_s_setprio(1);                                      \
        _Pragma("unroll") for (int ks = 0; ks < 2; ++ks)                    \
            _Pragma("unroll") for (int m2 = 0; m2 < 2; ++m2)                \
                _Pragma("unroll") for (int ni = 0; ni < 4; ++ni)            \
                    acc[(QD)*2 + m2][ni] =                                  \
                        __builtin_amdgcn_mfma_f32_16x16x32_bf16(            \
                            AF[m2][ks], bfr[ni][ks],                        \
                            acc[(QD)*2 + m2][ni], 0, 0, 0);                 \
        __builtin_amdgcn_s_setprio(0);                                      \
    } while (0)

__global__ __launch_bounds__(512, 2) void gemm_bt(
    const unsigned short* __restrict__ A,   // [M][K] bf16
    const unsigned short* __restrict__ B,   // [N][K] bf16 (W transposed)
    float* __restrict__ C) {                // [M][N] fp32
    const int K = DIN, N = DOUT;

    __shared__ __align__(16) unsigned short sA[2][BM * BK];  // 2 x 32 KB
    __shared__ __align__(16) unsigned short sB[2][BN * BK];  // 2 x 32 KB

    const int tid  = threadIdx.x;
    const int wave = tid >> 6;
    const int lane = tid & 63;
    const int wm = wave >> 2;               // 0..1  (M)
    const int wn = wave & 3;                // 0..3  (N)

    // ---- T1: XCD-aware bijective block swizzle (512 wgs, 8 XCDs, 64/XCD) ----
    const int wg  = blockIdx.x + gridDim.x * blockIdx.y;   // hardware linear id
    const int xcd = wg & 7;
    const int idx = wg >> 3;                               // 0..63 within XCD
    const int bx  = (xcd & 1) * 8 + (idx & 7);             // 0..15  (N tiles)
    const int by  = (xcd >> 1) * 8 + (idx >> 3);           // 0..31  (M tiles)

    // ---- staging addressing: wave w stages rows 16w..16w+15 of each half ----
    const int lrow = lane >> 3;             // 0..7 row within 8-row chunk
    const int qsrc = (lane & 7) ^ lrow;     // pre-swizzled global k-quad
    const unsigned short* gA =
        A + (size_t)(by * BM + wave * 16 + lrow) * K + qsrc * 8;
    const unsigned short* gB =
        B + (size_t)(bx * BN + wave * 16 + lrow) * K + qsrc * 8;

    // ---- fragment read addressing (swizzled ds_read) ----
    const int mrow = lane & 15;
    const int kgrp = lane >> 4;             // 0..3
    const int xr   = lane & 7;              // = row&7 of the frag row
    const int q80  = ((kgrp ^ xr) << 3);        // ks=0 swizzled quad * 8
    const int q81  = (((4 | kgrp) ^ xr) << 3);  // ks=1
    const int rowA = (wm * 128 + mrow) << 6;    // *64 elems/row
    const int rowB = (wn * 64 + mrow) << 6;

    f32x4 acc[8][4];
#pragma unroll
    for (int i = 0; i < 8; ++i)
#pragma unroll
        for (int j = 0; j < 4; ++j) {
            f32x4 z = {0.f, 0.f, 0.f, 0.f};
            acc[i][j] = z;
        }
    bf16x8 bfr[4][2];     // B-frags: resident across a K-tile's 4 phases
    bf16x8 afA[2][2];     // A-frag ping
    bf16x8 afB[2][2];     // A-frag pong

    // ---- prologue: A0, B0, B1 (12 gloads); VM4 confirms A0,B0; B1 flies ----
    STAGE_A(0, 0, 0);
    STAGE_A(0, 1, 0);
    STAGE_B(0, 0, 0);
    STAGE_B(0, 1, 0);
    STAGE_B(1, 0, 64);
    STAGE_B(1, 1, 64);
    VM4;
    BAR;
    RD_A(afA, 0, 0);      // tile0 Q0 (consumed at first p0)

    // ---- main loop: 31 iters (tiles 0..61), 8 phases, 1 barrier each ----
    for (int kt = 0; kt + 256 <= K; kt += 128) {
        // p0: B0-burst (pinned first) + A0Q1 ahead; MFMA Q0(buf0)
        RD_B(0); SB0; RD_A(afB, 0, 1);
        STAGE_A(1, 0, kt + 64);
        BAR; LGK4; SB0; MM(afA, 0);
        // p1
        RD_A(afA, 0, 2);
        STAGE_A(1, 1, kt + 64);
        BAR; LGK4; SB0; MM(afB, 1);
        // p2: VM2 confirms leftover B1 + A@kt+64 before BAR (p3 reads sA[1])
        RD_A(afB, 0, 3);
        STAGE_B(0, 0, kt + 128);
        VM2;
        BAR; LGK4; SB0; MM(afA, 2);
        // p3
        RD_A(afA, 1, 0);
        STAGE_B(0, 1, kt + 128);
        BAR; LGK4; SB0; MM(afB, 3);
        // p4: B1-burst + A1Q1; MFMA Q0(buf1)
        RD_B(1); SB0; RD_A(afB, 1, 1);
        STAGE_A(0, 0, kt + 128);
        BAR; LGK4; SB0; MM(afA, 0);
        // p5
        RD_A(afA, 1, 2);
        STAGE_A(0, 1, kt + 128);
        BAR; LGK4; SB0; MM(afB, 1);
        // p6: VM2 confirms B@kt+128 + A@kt+128 before BAR (p7/next-p0 reads)
        RD_A(afB, 1, 3);
        STAGE_B(1, 0, kt + 192);
        VM2;
        BAR; LGK4; SB0; MM(afA, 2);
        // p7: read next tile0's Q0 from re-staged sA[0]
        RD_A(afA, 0, 0);
        STAGE_B(1, 1, kt + 192);
        BAR; LGK4; SB0; MM(afB, 3);
    }

    // ---- peeled tail: tiles 62 (buf0) and 63 (buf1) ----
    {
        RD_B(0); SB0; RD_A(afB, 0, 1);
        STAGE_A(1, 0, K - 64);
        BAR; LGK4; SB0; MM(afA, 0);

        RD_A(afA, 0, 2);
        STAGE_A(1, 1, K - 64);
        BAR; LGK4; SB0; MM(afB, 1);

        RD_A(afB, 0, 3);
        VM0;              // confirm B63 + A63 fully; no more stages
        BAR; LGK4; SB0; MM(afA, 2);

        RD_A(afA, 1, 0);
        BAR; LGK4; SB0; MM(afB, 3);

        RD_B(1); SB0; RD_A(afB, 1, 1);
        BAR; LGK4; SB0; MM(afA, 0);

        RD_A(afA, 1, 2);
        BAR; LGK4; SB0; MM(afB, 1);

        RD_A(afB, 1, 3);
        BAR; LGK4; SB0; MM(afA, 2);

        LGK0; SB0; MM(afB, 3);
    }

    // ---- epilogue: C/D layout col=lane&15, row=(lane>>4)*4+reg; NT stores ----
    float* Cw = C + (size_t)(by * BM + wm * 128 + kgrp * 4) * N
                + (size_t)(bx * BN + wn * 64 + mrow);
#pragma unroll
    for (int mi = 0; mi < 8; ++mi)
#pragma unroll
        for (int ni = 0; ni < 4; ++ni)
#pragma unroll
            for (int r = 0; r < 4; ++r)
                __builtin_nontemporal_store(acc[mi][ni][r],
                                            &Cw[(size_t)(mi * 16 + r) * N + ni * 16]);
}

// ============ safety-net fallback if ws is too small (slow but correct) ============
__global__ void gemm_naive(const float* __restrict__ x, const int* __restrict__ W,
                           float* __restrict__ out) {
    int n = blockIdx.x * blockDim.x + threadIdx.x;
    int t = blockIdx.y;
    const float* xr = x + (size_t)t * DIN;
    float acc = 0.f;
    for (int k = 0; k < DIN; ++k)
        acc += xr[k] * (float)W[(size_t)k * DOUT + n];
    out[(size_t)t * DOUT + n] = acc;
}

extern "C" void kernel_launch(void* const* d_in, const int* in_sizes, int n_in,
                              void* d_out, int out_size, void* d_ws, size_t ws_size,
                              hipStream_t stream) {
    const float* x = (const float*)d_in[0];
    const int*   W = (const int*)d_in[1];
    float* out = (float*)d_out;

    const size_t xb_elems = (size_t)TOKENS * DIN;           // 64 MB bf16
    const size_t wt_elems = (size_t)DIN * DOUT;             // 32 MB bf16
    const size_t need = (xb_elems + wt_elems) * sizeof(unsigned short);

    if (ws_size < need) {   // should not happen; correctness safety net
        dim3 g(DOUT / 256, TOKENS);
        gemm_naive<<<g, 256, 0, stream>>>(x, W, out);
        return;
    }

    unsigned short* xb = (unsigned short*)d_ws;
    unsigned short* Wt = xb + xb_elems;

    fused_cvt<<<WBLKS + XBLKS, 256, 0, stream>>>(x, W, xb, Wt);

    dim3 grid(DOUT / BN, TOKENS / BM);   // (16, 32)
    gemm_bt<<<grid, 512, 0, stream>>>(xb, Wt, out);
}